// Round 5
// baseline (712.113 us; speedup 1.0000x reference)
//
#include <hip/hip_runtime.h>

// Flow_49160195670664: Dopri5 fixed-step integration of dx/dt = A x + B u(t),
// T=32768, N=256, NI=NO=32, dt=1, Hermite-interpolated stage inputs.
// Linear system => x_{n+1} = R x_n + v_n with constant R; 2-level blocked
// parallel scan (32 x 32 x 32), fp32 throughout.

#define TPTS 32768

struct GemmParams {
  const float* A[16];
  const float* B[16];
  float* C[16];
  float* Ct[16];              // optional transposed store (for W-stack fusion)
  int M, K, ksplit, atomic;   // N fixed at 256
};

// C[M][256] (+)= A[M][K] @ B[K][256], row-major, BM=BN=64, BK=16, 4x4 micro-tile.
__global__ __launch_bounds__(256) void gemm_f32(GemmParams p) {
  int bz = blockIdx.z;
  int batch = bz / p.ksplit;
  int split = bz - batch * p.ksplit;
  const float* __restrict__ A = p.A[batch];
  const float* __restrict__ B = p.B[batch];
  float* __restrict__ C = p.C[batch];
  int m0 = blockIdx.x * 64, n0 = blockIdx.y * 64;
  int klen = p.K / p.ksplit;
  int k0 = split * klen;
  __shared__ float As[16][64];
  __shared__ float Bs[16][64];
  int tid = threadIdx.x;
  int tx = tid & 15, ty = tid >> 4;
  int amm = tid >> 2, akk = (tid & 3) << 2;
  int bkk = tid >> 4, bnn = (tid & 15) << 2;
  float acc[4][4] = {{0.f}};
  for (int kt = k0; kt < k0 + klen; kt += 16) {
    float4 av = make_float4(0.f, 0.f, 0.f, 0.f);
    if (m0 + amm < p.M) av = *(const float4*)(A + (size_t)(m0 + amm) * p.K + kt + akk);
    float4 bv = *(const float4*)(B + (size_t)(kt + bkk) * 256 + n0 + bnn);
    __syncthreads();
    As[akk + 0][amm] = av.x;
    As[akk + 1][amm] = av.y;
    As[akk + 2][amm] = av.z;
    As[akk + 3][amm] = av.w;
    *(float4*)&Bs[bkk][bnn] = bv;
    __syncthreads();
#pragma unroll
    for (int kk = 0; kk < 16; kk++) {
      float4 a = *(const float4*)&As[kk][ty << 2];
      float4 b = *(const float4*)&Bs[kk][tx << 2];
      acc[0][0] += a.x * b.x; acc[0][1] += a.x * b.y; acc[0][2] += a.x * b.z; acc[0][3] += a.x * b.w;
      acc[1][0] += a.y * b.x; acc[1][1] += a.y * b.y; acc[1][2] += a.y * b.z; acc[1][3] += a.y * b.w;
      acc[2][0] += a.z * b.x; acc[2][1] += a.z * b.y; acc[2][2] += a.z * b.z; acc[2][3] += a.z * b.w;
      acc[3][0] += a.w * b.x; acc[3][1] += a.w * b.y; acc[3][2] += a.w * b.z; acc[3][3] += a.w * b.w;
    }
  }
  int rbase = m0 + (ty << 2), cbase = n0 + (tx << 2);
  if (p.atomic) {
#pragma unroll
    for (int i2 = 0; i2 < 4; i2++) {
      if (rbase + i2 < p.M) {
#pragma unroll
        for (int j2 = 0; j2 < 4; j2++)
          atomicAdd(&C[(size_t)(rbase + i2) * 256 + cbase + j2], acc[i2][j2]);
      }
    }
  } else {
#pragma unroll
    for (int i2 = 0; i2 < 4; i2++) {
      if (rbase + i2 < p.M)
        *(float4*)&C[(size_t)(rbase + i2) * 256 + cbase] =
            make_float4(acc[i2][0], acc[i2][1], acc[i2][2], acc[i2][3]);
    }
  }
  float* __restrict__ Ct = p.Ct[batch];
  if (Ct) {
#pragma unroll
    for (int i2 = 0; i2 < 4; i2++)
#pragma unroll
      for (int j2 = 0; j2 < 4; j2++)
        Ct[(size_t)(cbase + j2) * 256 + rbase + i2] = acc[i2][j2];
  }
}

// High-throughput fp32 GEMM: C[M][256] = A[M][K] @ B[K][256] (N fixed 256),
// BM=BN=128, BK=8, 256 threads, 8x8 micro-tile. Split-K writes partials to
// C + split*cstride (deterministic; no atomics).
__global__ __launch_bounds__(256) void gemm128(const float* __restrict__ A, const float* __restrict__ B,
                                               float* __restrict__ C, int M, int K, int ksplit,
                                               size_t cstride) {
  int m0 = blockIdx.x * 128, n0 = blockIdx.y * 128;
  int split = blockIdx.z;
  int klen = K / ksplit;
  int k0 = split * klen;
  float* __restrict__ Cw = C + (size_t)split * cstride;
  __shared__ float As[8][128];
  __shared__ float Bs[8][128];
  int tid = threadIdx.x;
  int am = tid >> 1, akc = (tid & 1) * 4;
  int bk = tid >> 5, bn = (tid & 31) * 4;
  int ty = tid >> 4, tx = tid & 15;
  float acc[8][8] = {{0.f}};
  for (int kt = k0; kt < k0 + klen; kt += 8) {
    float4 av = make_float4(0.f, 0.f, 0.f, 0.f);
    if (m0 + am < M) av = *(const float4*)(A + (size_t)(m0 + am) * K + kt + akc);
    float4 bv = *(const float4*)(B + (size_t)(kt + bk) * 256 + n0 + bn);
    __syncthreads();
    As[akc + 0][am] = av.x;
    As[akc + 1][am] = av.y;
    As[akc + 2][am] = av.z;
    As[akc + 3][am] = av.w;
    *(float4*)&Bs[bk][bn] = bv;
    __syncthreads();
#pragma unroll
    for (int kk = 0; kk < 8; kk++) {
      float4 a0 = *(const float4*)&As[kk][ty * 8];
      float4 a1 = *(const float4*)&As[kk][ty * 8 + 4];
      float4 b0 = *(const float4*)&Bs[kk][tx * 8];
      float4 b1 = *(const float4*)&Bs[kk][tx * 8 + 4];
      float ar[8] = {a0.x, a0.y, a0.z, a0.w, a1.x, a1.y, a1.z, a1.w};
      float br[8] = {b0.x, b0.y, b0.z, b0.w, b1.x, b1.y, b1.z, b1.w};
#pragma unroll
      for (int i = 0; i < 8; i++)
#pragma unroll
        for (int j = 0; j < 8; j++) acc[i][j] += ar[i] * br[j];
    }
  }
#pragma unroll
  for (int i = 0; i < 8; i++) {
    int row = m0 + ty * 8 + i;
    if (row < M) {
      *(float4*)&Cw[(size_t)row * 256 + n0 + tx * 8] = make_float4(acc[i][0], acc[i][1], acc[i][2], acc[i][3]);
      *(float4*)&Cw[(size_t)row * 256 + n0 + tx * 8 + 4] = make_float4(acc[i][4], acc[i][5], acc[i][6], acc[i][7]);
    }
  }
}

// dst[i] = sum over nsplit of src[s*elems + i]
__global__ __launch_bounds__(256) void reduce_splits(const float* __restrict__ src, float* __restrict__ dst,
                                                     int nsplit, int elems) {
  int idx = (blockIdx.x * 256 + threadIdx.x) * 4;
  if (idx >= elems) return;
  float4 a = make_float4(0.f, 0.f, 0.f, 0.f);
  for (int s = 0; s < nsplit; s++) {
    float4 v = *(const float4*)(src + (size_t)s * elems + idx);
    a.x += v.x; a.y += v.y; a.z += v.z; a.w += v.w;
  }
  *(float4*)(dst + idx) = a;
}

// AT = A^T (256x256), LDS 64x64 tiles, coalesced both sides.
__global__ __launch_bounds__(256) void transpose_at(const float* __restrict__ A, float* __restrict__ AT) {
  __shared__ float tile[64][65];
  int bx = blockIdx.x & 3, by = blockIdx.x >> 2;
  int r0 = by * 64, c0 = bx * 64;
  int t = threadIdx.x;
  int lr = t >> 4, lc = (t & 15) * 4;
  for (int rr = lr; rr < 64; rr += 16) {
    float4 v = *(const float4*)(A + (size_t)(r0 + rr) * 256 + c0 + lc);
    tile[rr][lc + 0] = v.x; tile[rr][lc + 1] = v.y; tile[rr][lc + 2] = v.z; tile[rr][lc + 3] = v.w;
  }
  __syncthreads();
  for (int rr = lr; rr < 64; rr += 16) {
    float4 v = make_float4(tile[lc + 0][rr], tile[lc + 1][rr], tile[lc + 2][rr], tile[lc + 3][rr]);
    *(float4*)(AT + (size_t)(c0 + rr) * 256 + r0 + lc) = v;
  }
}

// Unit responses through one Dopri5 step: cols 0..255 -> R (also R^T into W1T
// slot 30), cols 256..383 -> Hermite-folded tap matrices, transposed, into FcatT.
// Reads AT (=A^T) so lane i's dot-product loads AT[j*256+i] are COALESCED
// (round-4 version read A rows at 1KB lane stride -> 64-way split loads, 164us).
__global__ __launch_bounds__(256) void unit_resp(const float* __restrict__ AT,
                                                 const float* __restrict__ Bm,
                                                 float* __restrict__ Rout,
                                                 float* __restrict__ FcatT,
                                                 float* __restrict__ W1T) {
  int w = blockIdx.x;
  int i = threadIdx.x;
  __shared__ float xs4[256][4];

  const float AA[6][5] = {
      {0.f, 0.f, 0.f, 0.f, 0.f},
      {0.2f, 0.f, 0.f, 0.f, 0.f},
      {3.f / 40.f, 9.f / 40.f, 0.f, 0.f, 0.f},
      {44.f / 45.f, -56.f / 15.f, 32.f / 9.f, 0.f, 0.f},
      {19372.f / 6561.f, -25360.f / 2187.f, 64448.f / 6561.f, -212.f / 729.f, 0.f},
      {9017.f / 3168.f, -355.f / 33.f, 46732.f / 5247.f, 49.f / 176.f, -5103.f / 18656.f}};
  const float BB[6] = {35.f / 384.f, 0.f, 500.f / 1113.f, 125.f / 192.f, -2187.f / 6784.f, 11.f / 84.f};
  const float sv[6] = {0.f, 0.2f, 0.3f, 0.8f, 8.f / 9.f, 1.f};
  float Hm[6][4];
#pragma unroll
  for (int s = 0; s < 6; s++) {
    float ss = sv[s], s2 = ss * ss, s3 = s2 * ss;
    Hm[s][0] = 2.f * s3 - 3.f * s2 + 1.f;
    Hm[s][1] = s3 - 2.f * s2 + ss;
    Hm[s][2] = -2.f * s3 + 3.f * s2;
    Hm[s][3] = s3 - s2;
  }

  float xc[4];
  float kreg[6][4];
#pragma unroll
  for (int s = 0; s < 6; s++)
#pragma unroll
    for (int cc = 0; cc < 4; cc++) kreg[s][cc] = 0.f;

  int col[4], isF[4], tt[4];
  float brow[4];
#pragma unroll
  for (int cc = 0; cc < 4; cc++) {
    col[cc] = w * 4 + cc;
    if (col[cc] < 256) {
      isF[cc] = 0; tt[cc] = 0; brow[cc] = 0.f;
      xc[cc] = (i == col[cc]) ? 1.f : 0.f;
    } else {
      isF[cc] = 1; xc[cc] = 0.f;
      int f = col[cc] - 256;
      tt[cc] = f >> 5;
      brow[cc] = Bm[i * 32 + (f & 31)];
    }
  }
  float bh[6][4];
#pragma unroll
  for (int s = 0; s < 6; s++)
#pragma unroll
    for (int cc = 0; cc < 4; cc++) {
      float hv = (tt[cc] == 0) ? Hm[s][0] : ((tt[cc] == 1) ? Hm[s][1] : ((tt[cc] == 2) ? Hm[s][2] : Hm[s][3]));
      bh[s][cc] = isF[cc] ? hv * brow[cc] : 0.f;
    }

#pragma unroll
  for (int s = 0; s < 6; s++) {
#pragma unroll
    for (int cc = 0; cc < 4; cc++) {
      float v = xc[cc];
#pragma unroll
      for (int j = 0; j < 5; j++)
        if (j < s) v += AA[s][j] * kreg[j][cc];
      xs4[i][cc] = v;
    }
    __syncthreads();
    // k_s[i] = sum_j A[i][j] xs[j] = sum_j AT[j][i] xs[j]; AT load coalesced,
    // xs4[j] is a wave-uniform b128 broadcast. 4 independent fma chains.
    float ac[4] = {0.f, 0.f, 0.f, 0.f};
#pragma unroll 4
    for (int j = 0; j < 256; j++) {
      float a = AT[(size_t)j * 256 + i];
      float4 xv = *(const float4*)xs4[j];
      ac[0] += a * xv.x;
      ac[1] += a * xv.y;
      ac[2] += a * xv.z;
      ac[3] += a * xv.w;
    }
#pragma unroll
    for (int cc = 0; cc < 4; cc++) kreg[s][cc] = ac[cc] + bh[s][cc];
    __syncthreads();
  }
#pragma unroll
  for (int cc = 0; cc < 4; cc++) {
    float o = xc[cc];
#pragma unroll
    for (int s = 0; s < 6; s++) o += BB[s] * kreg[s][cc];
    if (!isF[cc]) {
      Rout[(size_t)i * 256 + col[cc]] = o;
      W1T[(size_t)(30 * 256 + col[cc]) * 256 + i] = o;   // (R^1)^T -> W1T slot 30
    } else {
      FcatT[(size_t)(col[cc] - 256) * 256 + i] = o;
    }
  }
}

// Identity into W1T slot 31 and W2T slot 31.
__global__ __launch_bounds__(256) void id_fill(float* __restrict__ W1T, float* __restrict__ W2T) {
  float* dst = (blockIdx.x == 0 ? W1T : W2T) + (size_t)31 * 65536;
  int n = threadIdx.x;
  for (int r4 = 0; r4 < 256; r4 += 4) {
    float4 v = make_float4(r4 == n ? 1.f : 0.f, r4 + 1 == n ? 1.f : 0.f,
                           r4 + 2 == n ? 1.f : 0.f, r4 + 3 == n ? 1.f : 0.f);
    *(float4*)&dst[(size_t)n * 256 + r4] = v;
  }
}

// Wtap[n][tap] = {u_n, m_n, u_{n+1}, m_{n+1}} taps; row 32767 = 0 (pad).
__global__ __launch_bounds__(128) void build_wtap(const float* __restrict__ u, float* __restrict__ Wtap) {
  int n = blockIdx.x;
  int tid = threadIdx.x;
  int t = tid >> 5, c = tid & 31;
  float val = 0.f;
  if (n < TPTS - 1) {
    if (t == 0) val = u[(size_t)n * 32 + c];
    else if (t == 2) val = u[(size_t)(n + 1) * 32 + c];
    else {
      int k = (t == 1) ? n : n + 1;
      if (k == 0) val = u[32 + c] - u[c];
      else if (k == TPTS - 1) val = u[(size_t)(TPTS - 1) * 32 + c] - u[(size_t)(TPTS - 2) * 32 + c];
      else val = 0.5f * (u[(size_t)(k + 1) * 32 + c] - u[(size_t)(k - 1) * 32 + c]);
    }
  }
  Wtap[(size_t)n * 128 + tid] = val;
}

// Top-level (stride-1024) starts; ||R^1024|| ~ 6e-5 so 2-term series is exact enough.
__global__ __launch_bounds__(256) void top_scan(const float* __restrict__ V2, const float* __restrict__ x0,
                                                const float* __restrict__ R1024, float* __restrict__ X2) {
  int k = blockIdx.x, i = threadIdx.x;
  if (k == 0) { X2[i] = x0[i]; return; }
  __shared__ float prev[256];
  const float* pv = (k == 1) ? x0 : (V2 + (size_t)(k - 2) * 256);
  prev[i] = pv[i];
  __syncthreads();
  float acc = V2[(size_t)(k - 1) * 256 + i];
  const float* rr = R1024 + (size_t)i * 256;
  for (int j = 0; j < 256; j += 4) {
    float4 rv = *(const float4*)(rr + j);
    acc += rv.x * prev[j] + rv.y * prev[j + 1] + rv.z * prev[j + 2] + rv.w * prev[j + 3];
  }
  X2[(size_t)k * 256 + i] = acc;
}

// Expand one level: NCH chains per block, 31 steps x <- Rm x + v. Inner loop is
// vmem-free (V staged in LDS per phase, outputs staged in hist). CH=6 keeps
// total LDS ~29KB so 2 blocks/CU co-reside and barrier bubbles overlap.
template <int NCH>
__global__ __launch_bounds__(512, 2) void expand_scan(const float* __restrict__ Rm,
                                                      const float* __restrict__ Xst,
                                                      const float* __restrict__ V,
                                                      float* __restrict__ Xout) {
  constexpr int CH = 6;   // rows per phase
  int blk = blockIdx.x;
  int t = threadIdx.x;
  int w = t >> 6, l = t & 63;
  int rg = l >> 3, cg = l & 7;
  int r0 = w * 32 + rg * 4;
  int c0 = cg * 32;
  float4 rr[4][8];
#pragma unroll
  for (int row = 0; row < 4; row++)
#pragma unroll
    for (int i = 0; i < 8; i++)
      rr[row][i] = *(const float4*)(Rm + (size_t)(r0 + row) * 256 + c0 + 4 * i);
  asm volatile("" ::: "memory");
  __shared__ float xbuf[2][NCH][288];          // padded: word f(q)=q+(q>>5)*4
  __shared__ float vbuf[CH][NCH][256];
  __shared__ float hist[CH][NCH][256];
  size_t gbase[NCH];
#pragma unroll
  for (int c = 0; c < NCH; c++) gbase[c] = ((size_t)blk * NCH + c) * 32 * 256;
  for (int e = t; e < NCH * 64; e += 512) {
    int c = e >> 6, q = (e & 63) * 4;
    float4 v4 = *(const float4*)(Xst + ((size_t)blk * NCH + c) * 256 + q);
    *(float4*)&xbuf[0][c][q + ((q >> 5) << 2)] = v4;
  }
  for (int ph = 0; ph * CH < 32; ph++) {
    int rb = ph * CH;
    int nr = (32 - rb < CH) ? (32 - rb) : CH;   // rows this phase
    int sb = (ph == 0) ? 0 : rb - 1;            // first step
    int se = rb + nr - 2;                       // last step (se<=30)
    int nv = se - sb + 1;
    for (int e = t; e < nv * NCH * 64; e += 512) {
      int jj = e / (NCH * 64);
      int r2 = e - jj * (NCH * 64);
      int c = r2 >> 6, q = (r2 & 63) * 4;
      *(float4*)&vbuf[jj][c][q] = *(const float4*)(V + gbase[c] + (size_t)(sb + jj) * 256 + q);
    }
    if (ph == 0) {
      for (int e = t; e < NCH * 64; e += 512) {
        int c = e >> 6, q = (e & 63) * 4;
        *(float4*)&hist[0][c][q] = *(const float4*)&xbuf[0][c][q + ((q >> 5) << 2)];
      }
    }
    __syncthreads();
    for (int s = sb; s <= se; s++) {
      float4 p[NCH];
#pragma unroll
      for (int c = 0; c < NCH; c++) p[c] = make_float4(0.f, 0.f, 0.f, 0.f);
#pragma unroll
      for (int i = 0; i < 8; i++) {
        int fi = cg * 36 + 4 * i;
#pragma unroll
        for (int c = 0; c < NCH; c++) {
          float4 xv = *(const float4*)&xbuf[s & 1][c][fi];
          p[c].x += rr[0][i].x * xv.x + rr[0][i].y * xv.y + rr[0][i].z * xv.z + rr[0][i].w * xv.w;
          p[c].y += rr[1][i].x * xv.x + rr[1][i].y * xv.y + rr[1][i].z * xv.z + rr[1][i].w * xv.w;
          p[c].z += rr[2][i].x * xv.x + rr[2][i].y * xv.y + rr[2][i].z * xv.z + rr[2][i].w * xv.w;
          p[c].w += rr[3][i].x * xv.x + rr[3][i].y * xv.y + rr[3][i].z * xv.z + rr[3][i].w * xv.w;
        }
      }
#pragma unroll
      for (int m = 1; m < 8; m <<= 1)
#pragma unroll
        for (int c = 0; c < NCH; c++) {
          p[c].x += __shfl_xor(p[c].x, m);
          p[c].y += __shfl_xor(p[c].y, m);
          p[c].z += __shfl_xor(p[c].z, m);
          p[c].w += __shfl_xor(p[c].w, m);
        }
      if (cg == 0) {
#pragma unroll
        for (int c = 0; c < NCH; c++) {
          float4 vd = *(const float4*)&vbuf[s - sb][c][r0];
          float4 nx = make_float4(p[c].x + vd.x, p[c].y + vd.y, p[c].z + vd.z, p[c].w + vd.w);
          *(float4*)&xbuf[(s + 1) & 1][c][w * 36 + rg * 4] = nx;
          *(float4*)&hist[s + 1 - rb][c][r0] = nx;
        }
      }
      __syncthreads();
    }
    for (int e = t; e < nr * NCH * 64; e += 512) {
      int jj = e / (NCH * 64);
      int r2 = e - jj * (NCH * 64);
      int c = r2 >> 6, q = (r2 & 63) * 4;
      *(float4*)(Xout + gbase[c] + (size_t)(rb + jj) * 256 + q) = *(const float4*)&hist[jj][c][q];
    }
    __syncthreads();
  }
}

// y = x @ C^T + u @ D^T
__global__ __launch_bounds__(256) void y_kernel(const float* __restrict__ x, const float* __restrict__ u,
                                                const float* __restrict__ Cm, const float* __restrict__ Dm,
                                                float* __restrict__ y) {
  __shared__ float Cs[32][260];
  __shared__ float Ds[32][32];
  __shared__ float xs[8][256];
  __shared__ float us[8][32];
  int tid = threadIdx.x;
  for (int k = tid; k < 8192; k += 256) Cs[k >> 8][k & 255] = Cm[k];
  for (int k = tid; k < 1024; k += 256) Ds[k >> 5][k & 31] = Dm[k];
  int o = tid & 31, rr = tid >> 5;
  int n0 = blockIdx.x * 64;
  for (int g = 0; g < 8; g++) {
    int nb = n0 + g * 8;
    __syncthreads();
    for (int k = tid; k < 2048; k += 256)
      xs[k >> 8][k & 255] = x[(size_t)(nb + (k >> 8)) * 256 + (k & 255)];
    for (int k = tid; k < 256; k += 256)
      us[k >> 5][k & 31] = u[(size_t)(nb + (k >> 5)) * 32 + (k & 31)];
    __syncthreads();
    float acc = 0.f;
    for (int i = 0; i < 256; i += 4) {
      float4 cv = *(const float4*)&Cs[o][i];
      float4 xv = *(const float4*)&xs[rr][i];
      acc += cv.x * xv.x + cv.y * xv.y + cv.z * xv.z + cv.w * xv.w;
    }
#pragma unroll
    for (int c = 0; c < 32; c += 4) {
      float4 dv = *(const float4*)&Ds[o][c];
      float4 uv = *(const float4*)&us[rr][c];
      acc += dv.x * uv.x + dv.y * uv.y + dv.z * uv.z + dv.w * uv.w;
    }
    y[(size_t)(nb + rr) * 32 + o] = acc;
  }
}

static void launch_gemm(hipStream_t s, int nb, const float* const* Aa, const float* const* Bb,
                        float* const* Cc, float* const* Ctt, int M, int K, int ksplit, int at) {
  GemmParams p;
  p.M = M; p.K = K; p.ksplit = ksplit; p.atomic = at;
  for (int i = 0; i < nb; i++) {
    p.A[i] = Aa[i]; p.B[i] = Bb[i]; p.C[i] = Cc[i];
    p.Ct[i] = Ctt ? Ctt[i] : nullptr;
  }
  for (int i = nb; i < 16; i++) { p.A[i] = nullptr; p.B[i] = nullptr; p.C[i] = nullptr; p.Ct[i] = nullptr; }
  dim3 g((M + 63) / 64, 4, nb * ksplit);
  gemm_f32<<<g, dim3(256), 0, s>>>(p);
}

extern "C" void kernel_launch(void* const* d_in, const int* in_sizes, int n_in,
                              void* d_out, int out_size, void* d_ws, size_t ws_size,
                              hipStream_t stream) {
  const float* u  = (const float*)d_in[1];
  const float* x0 = (const float*)d_in[2];
  const float* A  = (const float*)d_in[3];
  const float* Bm = (const float*)d_in[4];
  const float* Cm = (const float*)d_in[5];
  const float* Dm = (const float*)d_in[6];
  float* xout = (float*)d_out;                       // [32768][256]
  float* yout = xout + (size_t)TPTS * 256;           // [32768][32]

  char* wsb = (char*)d_ws;
  size_t off = 0;
  auto alloc = [&](size_t bytes) -> float* {
    float* p = (float*)(wsb + off);
    off = (off + bytes + 255) & ~(size_t)255;
    return p;
  };
  float* Rpow   = alloc(33ull * 65536 * 4);
  float* R32pow = alloc(33ull * 65536 * 4);
  float* ATm    = alloc(65536ull * 4);
  float* FcatT  = alloc(128ull * 256 * 4);
  float* W1T    = alloc(8192ull * 256 * 4);
  float* W2T    = alloc(8192ull * 256 * 4);
  float* Wtap   = alloc((size_t)TPTS * 128 * 4);
  float* V0     = alloc((size_t)TPTS * 256 * 4);
  float* V1     = alloc(1024ull * 256 * 4);
  float* V1p    = alloc(16ull * 1024 * 256 * 4);
  float* V2     = alloc(32ull * 256 * 4);
  float* X2     = alloc(32ull * 256 * 4);
  float* X1     = alloc(1024ull * 256 * 4);
  (void)ws_size; (void)in_sizes; (void)n_in; (void)out_size;

  auto RP = [&](int p) -> float* { return Rpow + (size_t)p * 65536; };
  auto QP = [&](int p) -> float* { return R32pow + (size_t)p * 65536; };
  auto W1S = [&](int s) -> float* { return W1T + (size_t)s * 65536; };
  auto W2S = [&](int s) -> float* { return W2T + (size_t)s * 65536; };

  // 1. A^T, then unit responses -> R (+R^T into W1T slot 30) and FcatT; identity slots
  transpose_at<<<dim3(16), dim3(256), 0, stream>>>(A, ATm);
  unit_resp<<<dim3(96), dim3(256), 0, stream>>>(ATm, Bm, RP(1), FcatT, W1T);
  id_fill<<<dim3(2), dim3(256), 0, stream>>>(W1T, W2T);

  // 2. powers of R; transposed copies go straight into the W stacks (slot 31-p)
  {
    const float* a[16]; const float* b[16]; float* c[16]; float* ct[16];
    a[0] = RP(1); b[0] = RP(1); c[0] = RP(2); ct[0] = W1S(29);
    launch_gemm(stream, 1, a, b, c, ct, 256, 256, 1, 0);
    a[0] = RP(2); b[0] = RP(1); c[0] = RP(3); ct[0] = W1S(28);
    a[1] = RP(2); b[1] = RP(2); c[1] = RP(4); ct[1] = W1S(27);
    launch_gemm(stream, 2, a, b, c, ct, 256, 256, 1, 0);
    for (int k = 1; k <= 4; k++) { a[k-1] = RP(4); b[k-1] = RP(k); c[k-1] = RP(4+k); ct[k-1] = W1S(31-(4+k)); }
    launch_gemm(stream, 4, a, b, c, ct, 256, 256, 1, 0);
    for (int k = 1; k <= 8; k++) { a[k-1] = RP(8); b[k-1] = RP(k); c[k-1] = RP(8+k); ct[k-1] = W1S(31-(8+k)); }
    launch_gemm(stream, 8, a, b, c, ct, 256, 256, 1, 0);
    for (int k = 1; k <= 16; k++) {
      int pw = 16 + k;
      a[k-1] = RP(16); b[k-1] = RP(k); c[k-1] = RP(pw);
      ct[k-1] = (pw == 32) ? W2S(30) : W1S(31 - pw);     // R^32 = Q^1 -> W2T slot 30
    }
    launch_gemm(stream, 16, a, b, c, ct, 256, 256, 1, 0);
    // powers of R32 = Q
    auto QS = [&](int pp) -> const float* { return (pp == 1) ? (const float*)RP(32) : (const float*)QP(pp); };
    a[0] = QS(1); b[0] = QS(1); c[0] = QP(2); ct[0] = W2S(29);
    launch_gemm(stream, 1, a, b, c, ct, 256, 256, 1, 0);
    a[0] = QP(2); b[0] = QS(1); c[0] = QP(3); ct[0] = W2S(28);
    a[1] = QP(2); b[1] = QP(2); c[1] = QP(4); ct[1] = W2S(27);
    launch_gemm(stream, 2, a, b, c, ct, 256, 256, 1, 0);
    for (int k = 1; k <= 4; k++) { a[k-1] = QP(4); b[k-1] = QS(k); c[k-1] = QP(4+k); ct[k-1] = W2S(31-(4+k)); }
    launch_gemm(stream, 4, a, b, c, ct, 256, 256, 1, 0);
    for (int k = 1; k <= 8; k++) { a[k-1] = QP(8); b[k-1] = QS(k); c[k-1] = QP(8+k); ct[k-1] = W2S(31-(8+k)); }
    launch_gemm(stream, 8, a, b, c, ct, 256, 256, 1, 0);
    for (int k = 1; k <= 16; k++) {
      int pw = 16 + k;
      a[k-1] = QP(16); b[k-1] = QS(k); c[k-1] = QP(pw);
      ct[k-1] = (pw == 32) ? nullptr : W2S(31 - pw);     // Q^32 = R^1024: no transpose needed
    }
    launch_gemm(stream, 16, a, b, c, ct, 256, 256, 1, 0);
  }

  // 3. Hermite taps and per-step drive v_n
  build_wtap<<<dim3(TPTS), dim3(128), 0, stream>>>(u, Wtap);
  gemm128<<<dim3(256, 2, 1), dim3(256), 0, stream>>>(Wtap, FcatT, V0, TPTS, 128, 1, 0);

  // 4. level-1 reduce: V1[j] = sum_i R^(31-i) v_{32j+i}  (split-K=16, deterministic)
  gemm128<<<dim3(8, 2, 16), dim3(256), 0, stream>>>(V0, W1T, V1p, 1024, 8192, 16, (size_t)1024 * 256);
  reduce_splits<<<dim3(256), dim3(256), 0, stream>>>(V1p, V1, 16, 1024 * 256);

  // 5. level-2 reduce: V2[k] = sum_j Q^(31-j) V1[32k+j]
  hipMemsetAsync(V2, 0, 32ull * 256 * 4, stream);
  {
    const float* a[1] = {V1}; const float* b[1] = {W2T}; float* c[1] = {V2};
    launch_gemm(stream, 1, a, b, c, nullptr, 32, 8192, 8, 1);
  }

  // 6. top starts, then expand down two levels
  top_scan<<<dim3(32), dim3(256), 0, stream>>>(V2, x0, QP(32), X2);
  expand_scan<1><<<dim3(32), dim3(512), 0, stream>>>(RP(32), X2, V1, X1);
  expand_scan<2><<<dim3(512), dim3(512), 0, stream>>>(RP(1), X1, V0, xout);

  // 7. outputs y
  y_kernel<<<dim3(512), dim3(256), 0, stream>>>(xout, u, Cm, Dm, yout);
}

// Round 6
// 575.828 us; speedup vs baseline: 1.2367x; 1.2367x over previous
//
#include <hip/hip_runtime.h>

// Flow_49160195670664: Dopri5 fixed-step integration of dx/dt = A x + B u(t),
// T=32768, N=256, NI=NO=32, dt=1, Hermite-interpolated stage inputs.
// Linear system => x_{n+1} = R x_n + v_n with constant R; 2-level blocked
// parallel scan (32 x 32 x 32). Sequential-chain parts run on MFMA with
// bf16 hi/lo split (x*R ~ xh*Rh + xl*Rh + xh*Rl, fp32 accumulate).

#define TPTS 32768

typedef __attribute__((ext_vector_type(8))) short short8;
typedef __attribute__((ext_vector_type(4))) float float4v;
typedef unsigned short ushort_t;

__device__ __forceinline__ ushort_t bf16_hi(float f) {
  unsigned u = __builtin_bit_cast(unsigned, f);
  unsigned r = (u + 0x7FFFu + ((u >> 16) & 1u)) >> 16;
  return (ushort_t)r;
}
__device__ __forceinline__ float bf16_f(ushort_t h) {
  unsigned u = ((unsigned)h) << 16;
  return __builtin_bit_cast(float, u);
}

// ---------------------------------------------------------------------------
// Unified MFMA chain kernel. 512 thr = 8 waves; wave w owns output cols
// [32w,32w+32) as 2 N-tiles of mfma_f32_16x16x32_bf16. 16 chains = MFMA M-dim.
// R^T held as B-frags in registers (Mh/Ml are NON-restrict so the asm clobber
// makes rematerialization illegal -> true VGPR residency; rounds 2-5 lesson).
// x lives in LDS as bf16 hi/lo, double-buffered; one barrier per step.
// MODE 0: power  (32 steps, no drive, x0 = I columns; Out=R^S row-major + h/l split)
// MODE 1: reduce (31 steps, drive V, x0 = V row0; Out[chain] = final x)
// MODE 2: expand (31 steps, drive V, x0 = X0; Out rows chain*32+j = all states)
template <int MODE>
__global__ __launch_bounds__(512, 2) void chain_mfma(const ushort_t* Mh, const ushort_t* Ml,
                                                     const float* X0, const float* V,
                                                     float* Out, ushort_t* OutH, ushort_t* OutL) {
  constexpr int STEPS = (MODE == 0) ? 32 : 31;
  constexpr int VP = (MODE == 0) ? 1 : 6;
  int blk = blockIdx.x, t = threadIdx.x;
  int w = t >> 6, l = t & 63;
  int q = l >> 4, c16 = l & 15;
  int n0 = w * 32;
  // B-frags: B[k][n] = R[n][k]; lane holds B[kt*32+q*8+j][n0+nt*16+c16], j=0..7
  short8 bh[2][8], bl[2][8];
#pragma unroll
  for (int nt = 0; nt < 2; nt++)
#pragma unroll
    for (int kt = 0; kt < 8; kt++) {
      size_t offs = (size_t)(n0 + nt * 16 + c16) * 256 + kt * 32 + q * 8;
      bh[nt][kt] = *(const short8*)(Mh + offs);
      bl[nt][kt] = *(const short8*)(Ml + offs);
    }
  asm volatile("" ::: "memory");   // Mh/Ml NOT restrict => loads cannot be re-issued
  __shared__ ushort_t xh[2][32][16][8];   // [buf][k>>3][chain][k&7]
  __shared__ ushort_t xl[2][32][16][8];
  __shared__ float vbuf[VP][16][256];
  // initial x
  for (int e = t; e < 1024; e += 512) {
    int c = e >> 6, qq = (e & 63) * 4;
    int cg = blk * 16 + c;
    float4 v4;
    if (MODE == 0) {
      v4 = make_float4(qq == cg ? 1.f : 0.f, qq + 1 == cg ? 1.f : 0.f,
                       qq + 2 == cg ? 1.f : 0.f, qq + 3 == cg ? 1.f : 0.f);
    } else if (MODE == 1) {
      v4 = *(const float4*)(V + (size_t)cg * 32 * 256 + qq);
    } else {
      v4 = *(const float4*)(X0 + (size_t)cg * 256 + qq);
      *(float4*)(Out + ((size_t)cg * 32) * 256 + qq) = v4;
    }
    float vals[4] = {v4.x, v4.y, v4.z, v4.w};
#pragma unroll
    for (int i = 0; i < 4; i++) {
      int n = qq + i;
      ushort_t h = bf16_hi(vals[i]);
      xh[0][n >> 3][c][n & 7] = h;
      xl[0][n >> 3][c][n & 7] = bf16_hi(vals[i] - bf16_f(h));
    }
  }
  __syncthreads();
  for (int s = 1; s <= STEPS; s++) {
    int cur = (s - 1) & 1, nxt = s & 1;
    bool newphase = (MODE != 0) && (((s - 1) % VP) == 0);
    if (newphase) {
      int nst = (STEPS - s + 1 < VP) ? (STEPS - s + 1) : VP;
      for (int e = t; e < nst * 1024; e += 512) {
        int jj = e >> 10;
        int r2 = e & 1023;
        int c = r2 >> 6, qq = (r2 & 63) * 4;
        int cg = blk * 16 + c;
        int drow = (MODE == 1) ? (s + jj) : (s + jj - 1);
        *(float4*)&vbuf[jj][c][qq] = *(const float4*)(V + ((size_t)cg * 32 + drow) * 256 + qq);
      }
    }
    float4v acc0 = {0.f, 0.f, 0.f, 0.f}, acc1 = {0.f, 0.f, 0.f, 0.f};
#pragma unroll
    for (int kt = 0; kt < 8; kt++) {
      short8 ah = *(const short8*)&xh[cur][kt * 4 + q][c16][0];
      short8 al = *(const short8*)&xl[cur][kt * 4 + q][c16][0];
      acc0 = __builtin_amdgcn_mfma_f32_16x16x32_bf16(ah, bh[0][kt], acc0, 0, 0, 0);
      acc1 = __builtin_amdgcn_mfma_f32_16x16x32_bf16(ah, bh[1][kt], acc1, 0, 0, 0);
      acc0 = __builtin_amdgcn_mfma_f32_16x16x32_bf16(al, bh[0][kt], acc0, 0, 0, 0);
      acc1 = __builtin_amdgcn_mfma_f32_16x16x32_bf16(al, bh[1][kt], acc1, 0, 0, 0);
      acc0 = __builtin_amdgcn_mfma_f32_16x16x32_bf16(ah, bl[0][kt], acc0, 0, 0, 0);
      acc1 = __builtin_amdgcn_mfma_f32_16x16x32_bf16(ah, bl[1][kt], acc1, 0, 0, 0);
    }
    if (newphase) __syncthreads();   // vbuf visible (uniform condition)
    int sj = (s - 1) % VP;
    // producer: C/D layout chain=(q*4+r), col=c16 (m89-verified)
#pragma unroll
    for (int nt = 0; nt < 2; nt++) {
#pragma unroll
      for (int r = 0; r < 4; r++) {
        int c = q * 4 + r;
        int n = n0 + nt * 16 + c16;
        float val = (nt == 0) ? acc0[r] : acc1[r];
        if (MODE != 0) val += vbuf[sj][c][n];
        int cg = blk * 16 + c;
        if (MODE == 2) Out[((size_t)cg * 32 + s) * 256 + n] = val;
        if (MODE == 1 && s == STEPS) Out[(size_t)cg * 256 + n] = val;
        if (MODE == 0 && s == STEPS) {
          ushort_t h2 = bf16_hi(val);
          Out[(size_t)n * 256 + cg] = val;
          OutH[(size_t)n * 256 + cg] = h2;
          OutL[(size_t)n * 256 + cg] = bf16_hi(val - bf16_f(h2));
        }
        ushort_t h = bf16_hi(val);
        xh[nxt][n >> 3][c][n & 7] = h;
        xl[nxt][n >> 3][c][n & 7] = bf16_hi(val - bf16_f(h));
      }
    }
    __syncthreads();
  }
}

// ---------------------------------------------------------------------------
// fp32 GEMM for the drive: C[M][256] = A[M][K] @ B[K][256], BM=BN=128, BK=8.
__global__ __launch_bounds__(256) void gemm128(const float* __restrict__ A, const float* __restrict__ B,
                                               float* __restrict__ C, int M, int K) {
  int m0 = blockIdx.x * 128, n0 = blockIdx.y * 128;
  __shared__ float As[8][128];
  __shared__ float Bs[8][128];
  int tid = threadIdx.x;
  int am = tid >> 1, akc = (tid & 1) * 4;
  int bk = tid >> 5, bn = (tid & 31) * 4;
  int ty = tid >> 4, tx = tid & 15;
  float acc[8][8] = {{0.f}};
  for (int kt = 0; kt < K; kt += 8) {
    float4 av = make_float4(0.f, 0.f, 0.f, 0.f);
    if (m0 + am < M) av = *(const float4*)(A + (size_t)(m0 + am) * K + kt + akc);
    float4 bv = *(const float4*)(B + (size_t)(kt + bk) * 256 + n0 + bn);
    __syncthreads();
    As[akc + 0][am] = av.x;
    As[akc + 1][am] = av.y;
    As[akc + 2][am] = av.z;
    As[akc + 3][am] = av.w;
    *(float4*)&Bs[bk][bn] = bv;
    __syncthreads();
#pragma unroll
    for (int kk = 0; kk < 8; kk++) {
      float4 a0 = *(const float4*)&As[kk][ty * 8];
      float4 a1 = *(const float4*)&As[kk][ty * 8 + 4];
      float4 b0 = *(const float4*)&Bs[kk][tx * 8];
      float4 b1 = *(const float4*)&Bs[kk][tx * 8 + 4];
      float ar[8] = {a0.x, a0.y, a0.z, a0.w, a1.x, a1.y, a1.z, a1.w};
      float br[8] = {b0.x, b0.y, b0.z, b0.w, b1.x, b1.y, b1.z, b1.w};
#pragma unroll
      for (int i = 0; i < 8; i++)
#pragma unroll
        for (int j = 0; j < 8; j++) acc[i][j] += ar[i] * br[j];
    }
  }
#pragma unroll
  for (int i = 0; i < 8; i++) {
    int row = m0 + ty * 8 + i;
    if (row < M) {
      *(float4*)&C[(size_t)row * 256 + n0 + tx * 8] = make_float4(acc[i][0], acc[i][1], acc[i][2], acc[i][3]);
      *(float4*)&C[(size_t)row * 256 + n0 + tx * 8 + 4] = make_float4(acc[i][4], acc[i][5], acc[i][6], acc[i][7]);
    }
  }
}

// AT = A^T (256x256)
__global__ __launch_bounds__(256) void transpose_at(const float* __restrict__ A, float* __restrict__ AT) {
  __shared__ float tile[64][65];
  int bx = blockIdx.x & 3, by = blockIdx.x >> 2;
  int r0 = by * 64, c0 = bx * 64;
  int t = threadIdx.x;
  int lr = t >> 4, lc = (t & 15) * 4;
  for (int rr = lr; rr < 64; rr += 16) {
    float4 v = *(const float4*)(A + (size_t)(r0 + rr) * 256 + c0 + lc);
    tile[rr][lc + 0] = v.x; tile[rr][lc + 1] = v.y; tile[rr][lc + 2] = v.z; tile[rr][lc + 3] = v.w;
  }
  __syncthreads();
  for (int rr = lr; rr < 64; rr += 16) {
    float4 v = make_float4(tile[lc + 0][rr], tile[lc + 1][rr], tile[lc + 2][rr], tile[lc + 3][rr]);
    *(float4*)(AT + (size_t)(c0 + rr) * 256 + r0 + lc) = v;
  }
}

// Unit responses through one Dopri5 step: cols 0..255 -> R fp32 + bf16 hi/lo
// split; cols 256..383 -> Hermite-folded tap matrices transposed into FcatT.
__global__ __launch_bounds__(256) void unit_resp(const float* __restrict__ AT,
                                                 const float* __restrict__ Bm,
                                                 float* __restrict__ Rout,
                                                 ushort_t* __restrict__ Rh,
                                                 ushort_t* __restrict__ Rl,
                                                 float* __restrict__ FcatT) {
  int w = blockIdx.x;
  int i = threadIdx.x;
  __shared__ float xs4[256][4];

  const float AA[6][5] = {
      {0.f, 0.f, 0.f, 0.f, 0.f},
      {0.2f, 0.f, 0.f, 0.f, 0.f},
      {3.f / 40.f, 9.f / 40.f, 0.f, 0.f, 0.f},
      {44.f / 45.f, -56.f / 15.f, 32.f / 9.f, 0.f, 0.f},
      {19372.f / 6561.f, -25360.f / 2187.f, 64448.f / 6561.f, -212.f / 729.f, 0.f},
      {9017.f / 3168.f, -355.f / 33.f, 46732.f / 5247.f, 49.f / 176.f, -5103.f / 18656.f}};
  const float BB[6] = {35.f / 384.f, 0.f, 500.f / 1113.f, 125.f / 192.f, -2187.f / 6784.f, 11.f / 84.f};
  const float sv[6] = {0.f, 0.2f, 0.3f, 0.8f, 8.f / 9.f, 1.f};
  float Hm[6][4];
#pragma unroll
  for (int s = 0; s < 6; s++) {
    float ss = sv[s], s2 = ss * ss, s3 = s2 * ss;
    Hm[s][0] = 2.f * s3 - 3.f * s2 + 1.f;
    Hm[s][1] = s3 - 2.f * s2 + ss;
    Hm[s][2] = -2.f * s3 + 3.f * s2;
    Hm[s][3] = s3 - s2;
  }

  float xc[4];
  float kreg[6][4];
#pragma unroll
  for (int s = 0; s < 6; s++)
#pragma unroll
    for (int cc = 0; cc < 4; cc++) kreg[s][cc] = 0.f;

  int col[4], isF[4], tt[4];
  float brow[4];
#pragma unroll
  for (int cc = 0; cc < 4; cc++) {
    col[cc] = w * 4 + cc;
    if (col[cc] < 256) {
      isF[cc] = 0; tt[cc] = 0; brow[cc] = 0.f;
      xc[cc] = (i == col[cc]) ? 1.f : 0.f;
    } else {
      isF[cc] = 1; xc[cc] = 0.f;
      int f = col[cc] - 256;
      tt[cc] = f >> 5;
      brow[cc] = Bm[i * 32 + (f & 31)];
    }
  }
  float bh[6][4];
#pragma unroll
  for (int s = 0; s < 6; s++)
#pragma unroll
    for (int cc = 0; cc < 4; cc++) {
      float hv = (tt[cc] == 0) ? Hm[s][0] : ((tt[cc] == 1) ? Hm[s][1] : ((tt[cc] == 2) ? Hm[s][2] : Hm[s][3]));
      bh[s][cc] = isF[cc] ? hv * brow[cc] : 0.f;
    }

#pragma unroll
  for (int s = 0; s < 6; s++) {
#pragma unroll
    for (int cc = 0; cc < 4; cc++) {
      float v = xc[cc];
#pragma unroll
      for (int j = 0; j < 5; j++)
        if (j < s) v += AA[s][j] * kreg[j][cc];
      xs4[i][cc] = v;
    }
    __syncthreads();
    float ac[4] = {0.f, 0.f, 0.f, 0.f};
#pragma unroll 4
    for (int j = 0; j < 256; j++) {
      float a = AT[(size_t)j * 256 + i];
      float4 xv = *(const float4*)xs4[j];
      ac[0] += a * xv.x;
      ac[1] += a * xv.y;
      ac[2] += a * xv.z;
      ac[3] += a * xv.w;
    }
#pragma unroll
    for (int cc = 0; cc < 4; cc++) kreg[s][cc] = ac[cc] + bh[s][cc];
    __syncthreads();
  }
#pragma unroll
  for (int cc = 0; cc < 4; cc++) {
    float o = xc[cc];
#pragma unroll
    for (int s = 0; s < 6; s++) o += BB[s] * kreg[s][cc];
    if (!isF[cc]) {
      Rout[(size_t)i * 256 + col[cc]] = o;
      ushort_t h = bf16_hi(o);
      Rh[(size_t)i * 256 + col[cc]] = h;
      Rl[(size_t)i * 256 + col[cc]] = bf16_hi(o - bf16_f(h));
    } else {
      FcatT[(size_t)(col[cc] - 256) * 256 + i] = o;
    }
  }
}

// Wtap[n][tap] = {u_n, m_n, u_{n+1}, m_{n+1}} taps; row 32767 = 0 (pad).
__global__ __launch_bounds__(128) void build_wtap(const float* __restrict__ u, float* __restrict__ Wtap) {
  int n = blockIdx.x;
  int tid = threadIdx.x;
  int t = tid >> 5, c = tid & 31;
  float val = 0.f;
  if (n < TPTS - 1) {
    if (t == 0) val = u[(size_t)n * 32 + c];
    else if (t == 2) val = u[(size_t)(n + 1) * 32 + c];
    else {
      int k = (t == 1) ? n : n + 1;
      if (k == 0) val = u[32 + c] - u[c];
      else if (k == TPTS - 1) val = u[(size_t)(TPTS - 1) * 32 + c] - u[(size_t)(TPTS - 2) * 32 + c];
      else val = 0.5f * (u[(size_t)(k + 1) * 32 + c] - u[(size_t)(k - 1) * 32 + c]);
    }
  }
  Wtap[(size_t)n * 128 + tid] = val;
}

// Top-level (stride-1024) starts; ||R^1024|| ~ 6e-5 so 2-term series suffices.
__global__ __launch_bounds__(256) void top_scan(const float* __restrict__ V2, const float* __restrict__ x0,
                                                const float* __restrict__ R1024, float* __restrict__ X2) {
  int k = blockIdx.x, i = threadIdx.x;
  if (k == 0) { X2[i] = x0[i]; return; }
  __shared__ float prev[256];
  const float* pv = (k == 1) ? x0 : (V2 + (size_t)(k - 2) * 256);
  prev[i] = pv[i];
  __syncthreads();
  float acc = V2[(size_t)(k - 1) * 256 + i];
  const float* rr = R1024 + (size_t)i * 256;
  for (int j = 0; j < 256; j += 4) {
    float4 rv = *(const float4*)(rr + j);
    acc += rv.x * prev[j] + rv.y * prev[j + 1] + rv.z * prev[j + 2] + rv.w * prev[j + 3];
  }
  X2[(size_t)k * 256 + i] = acc;
}

// y = x @ C^T + u @ D^T
__global__ __launch_bounds__(256) void y_kernel(const float* __restrict__ x, const float* __restrict__ u,
                                                const float* __restrict__ Cm, const float* __restrict__ Dm,
                                                float* __restrict__ y) {
  __shared__ float Cs[32][260];
  __shared__ float Ds[32][32];
  __shared__ float xs[8][256];
  __shared__ float us[8][32];
  int tid = threadIdx.x;
  for (int k = tid; k < 8192; k += 256) Cs[k >> 8][k & 255] = Cm[k];
  for (int k = tid; k < 1024; k += 256) Ds[k >> 5][k & 31] = Dm[k];
  int o = tid & 31, rr = tid >> 5;
  int n0 = blockIdx.x * 64;
  for (int g = 0; g < 8; g++) {
    int nb = n0 + g * 8;
    __syncthreads();
    for (int k = tid; k < 2048; k += 256)
      xs[k >> 8][k & 255] = x[(size_t)(nb + (k >> 8)) * 256 + (k & 255)];
    for (int k = tid; k < 256; k += 256)
      us[k >> 5][k & 31] = u[(size_t)(nb + (k >> 5)) * 32 + (k & 31)];
    __syncthreads();
    float acc = 0.f;
    for (int i = 0; i < 256; i += 4) {
      float4 cv = *(const float4*)&Cs[o][i];
      float4 xv = *(const float4*)&xs[rr][i];
      acc += cv.x * xv.x + cv.y * xv.y + cv.z * xv.z + cv.w * xv.w;
    }
#pragma unroll
    for (int c = 0; c < 32; c += 4) {
      float4 dv = *(const float4*)&Ds[o][c];
      float4 uv = *(const float4*)&us[rr][c];
      acc += dv.x * uv.x + dv.y * uv.y + dv.z * uv.z + dv.w * uv.w;
    }
    y[(size_t)(nb + rr) * 32 + o] = acc;
  }
}

extern "C" void kernel_launch(void* const* d_in, const int* in_sizes, int n_in,
                              void* d_out, int out_size, void* d_ws, size_t ws_size,
                              hipStream_t stream) {
  const float* u  = (const float*)d_in[1];
  const float* x0 = (const float*)d_in[2];
  const float* A  = (const float*)d_in[3];
  const float* Bm = (const float*)d_in[4];
  const float* Cm = (const float*)d_in[5];
  const float* Dm = (const float*)d_in[6];
  float* xout = (float*)d_out;                       // [32768][256]
  float* yout = xout + (size_t)TPTS * 256;           // [32768][32]

  char* wsb = (char*)d_ws;
  size_t off = 0;
  auto alloc = [&](size_t bytes) -> void* {
    void* p = (void*)(wsb + off);
    off = (off + bytes + 255) & ~(size_t)255;
    return p;
  };
  float*    Rfp    = (float*)alloc(65536 * 4);
  ushort_t* Rh     = (ushort_t*)alloc(65536 * 2);
  ushort_t* Rl     = (ushort_t*)alloc(65536 * 2);
  float*    R32fp  = (float*)alloc(65536 * 4);
  ushort_t* R32h   = (ushort_t*)alloc(65536 * 2);
  ushort_t* R32l   = (ushort_t*)alloc(65536 * 2);
  float*    RKfp   = (float*)alloc(65536 * 4);       // R^1024
  ushort_t* RKh    = (ushort_t*)alloc(65536 * 2);
  ushort_t* RKl    = (ushort_t*)alloc(65536 * 2);
  float*    ATm    = (float*)alloc(65536 * 4);
  float*    FcatT  = (float*)alloc(128 * 256 * 4);
  float*    Wtap   = (float*)alloc((size_t)TPTS * 128 * 4);
  float*    V0     = (float*)alloc((size_t)TPTS * 256 * 4);
  float*    V1     = (float*)alloc(1024 * 256 * 4);
  float*    V2     = (float*)alloc(32 * 256 * 4);
  float*    X2     = (float*)alloc(32 * 256 * 4);
  float*    X1     = (float*)alloc(1024 * 256 * 4);
  (void)ws_size; (void)in_sizes; (void)n_in; (void)out_size;

  // 1. A^T, unit responses -> R (fp32 + hi/lo split) and FcatT
  transpose_at<<<dim3(16), dim3(256), 0, stream>>>(A, ATm);
  unit_resp<<<dim3(96), dim3(256), 0, stream>>>(ATm, Bm, Rfp, Rh, Rl, FcatT);

  // 2. R^32 = 32 chained applications of R on unit columns; R^1024 likewise on R^32
  chain_mfma<0><<<dim3(16), dim3(512), 0, stream>>>(Rh, Rl, nullptr, nullptr, R32fp, R32h, R32l);
  chain_mfma<0><<<dim3(16), dim3(512), 0, stream>>>(R32h, R32l, nullptr, nullptr, RKfp, RKh, RKl);

  // 3. Hermite taps and per-step drive v_n (fp32 GEMM, K=128)
  build_wtap<<<dim3(TPTS), dim3(128), 0, stream>>>(u, Wtap);
  gemm128<<<dim3(256, 2), dim3(256), 0, stream>>>(Wtap, FcatT, V0, TPTS, 128);

  // 4. reduces: V1[j] = sum_i R^(31-i) v_{32j+i};  V2[k] = sum_j R32^(31-j) V1[32k+j]
  chain_mfma<1><<<dim3(64), dim3(512), 0, stream>>>(Rh, Rl, nullptr, V0, V1, nullptr, nullptr);
  chain_mfma<1><<<dim3(2), dim3(512), 0, stream>>>(R32h, R32l, nullptr, V1, V2, nullptr, nullptr);

  // 5. top starts, then expand down two levels
  top_scan<<<dim3(32), dim3(256), 0, stream>>>(V2, x0, RKfp, X2);
  chain_mfma<2><<<dim3(2), dim3(512), 0, stream>>>(R32h, R32l, X2, V1, X1, nullptr, nullptr);
  chain_mfma<2><<<dim3(64), dim3(512), 0, stream>>>(Rh, Rl, X1, V0, xout, nullptr, nullptr);

  // 6. outputs y
  y_kernel<<<dim3(512), dim3(256), 0, stream>>>(xout, u, Cm, Dm, yout);
}

// Round 7
// 521.077 us; speedup vs baseline: 1.3666x; 1.1051x over previous
//
#include <hip/hip_runtime.h>

// Flow_49160195670664: Dopri5 fixed-step integration of dx/dt = A x + B u(t),
// T=32768, N=256, NI=NO=32, dt=1, Hermite-interpolated stage inputs.
// Linear system => x_{n+1} = R x_n + v_n with constant R; 2-level blocked
// parallel scan (32 x 32 x 32). Sequential-chain parts run on MFMA with
// bf16 hi/lo split (x*R ~ xh*Rh + xl*Rh + xh*Rl, fp32 accumulate).

#define TPTS 32768

typedef __attribute__((ext_vector_type(8))) short short8;
typedef __attribute__((ext_vector_type(4))) float float4v;
typedef unsigned short ushort_t;

__device__ __forceinline__ ushort_t bf16_hi(float f) {
  unsigned u = __builtin_bit_cast(unsigned, f);
  unsigned r = (u + 0x7FFFu + ((u >> 16) & 1u)) >> 16;
  return (ushort_t)r;
}
__device__ __forceinline__ float bf16_f(ushort_t h) {
  unsigned u = ((unsigned)h) << 16;
  return __builtin_bit_cast(float, u);
}

// ---------------------------------------------------------------------------
// MFMA chain kernel v2. 512 thr = 8 waves; wave w owns output cols [32w,32w+32)
// as 2 N-tiles of mfma_f32_16x16x32_bf16; 16 chains = MFMA M-dim.
// R^T B-frags live in VGPRs, residency FORCED by per-value "+v" asm pins inside
// the loop (a rw-operand makes reload/remat illegal — the r2-r6 lesson; plain
// memory clobbers don't stop rematerialization, VGPR_Count was 88 not ~190).
// 6 independent accumulators cut dependent-MFMA depth 24 -> 8.
// V-drive is per-lane register-prefetched one step ahead (no vbuf LDS/barrier).
// MODE 2 stores go through a 5-slot LDS ring, flushed 4 rows per 4 steps just
// after a barrier so the global-store drain overlaps the next step's MFMAs.
// MODE 0: power  (32 steps, x0 = I cols; Out=R^32 row-major fp32 + h/l split)
// MODE 1: reduce (31 steps, x0 = V row0, drive rows 1..31; Out[chain] = final x)
// MODE 2: expand (31 steps, x0 = X0, drive rows 0..30; Out rows chain*32+j)
template <int MODE>
__global__ __launch_bounds__(512, 2) void chain_mfma(const ushort_t* Mh, const ushort_t* Ml,
                                                     const float* X0, const float* V,
                                                     float* Out, ushort_t* OutH, ushort_t* OutL) {
  constexpr int STEPS = (MODE == 0) ? 32 : 31;
  constexpr int HSLOTS = (MODE == 2) ? 5 : 1;
  int blk = blockIdx.x, t = threadIdx.x;
  int w = t >> 6, l = t & 63;
  int q = l >> 4, c16 = l & 15;
  int n0 = w * 32;
  // B-frags: B[k][n] = R[n][k]; lane holds B[kt*32+q*8+j][n0+nt*16+c16], j=0..7
  short8 bh[2][8], bl[2][8];
#pragma unroll
  for (int nt = 0; nt < 2; nt++)
#pragma unroll
    for (int kt = 0; kt < 8; kt++) {
      size_t offs = (size_t)(n0 + nt * 16 + c16) * 256 + kt * 32 + q * 8;
      bh[nt][kt] = *(const short8*)(Mh + offs);
      bl[nt][kt] = *(const short8*)(Ml + offs);
    }
  __shared__ __attribute__((aligned(16))) ushort_t xh[2][32][16][8];  // [buf][k>>3][chain][k&7]
  __shared__ __attribute__((aligned(16))) ushort_t xl[2][32][16][8];
  __shared__ float hist[HSLOTS][16][256];
  // initial x (and row-0 store for MODE 2)
  for (int e = t; e < 1024; e += 512) {
    int c = e >> 6, qq = (e & 63) * 4;
    int cg = blk * 16 + c;
    float4 v4;
    if (MODE == 0) {
      v4 = make_float4(qq == cg ? 1.f : 0.f, qq + 1 == cg ? 1.f : 0.f,
                       qq + 2 == cg ? 1.f : 0.f, qq + 3 == cg ? 1.f : 0.f);
    } else if (MODE == 1) {
      v4 = *(const float4*)(V + (size_t)cg * 32 * 256 + qq);
    } else {
      v4 = *(const float4*)(X0 + (size_t)cg * 256 + qq);
      *(float4*)(Out + ((size_t)cg * 32) * 256 + qq) = v4;
    }
    float vals[4] = {v4.x, v4.y, v4.z, v4.w};
#pragma unroll
    for (int i = 0; i < 4; i++) {
      int n = qq + i;
      ushort_t h = bf16_hi(vals[i]);
      xh[0][n >> 3][c][n & 7] = h;
      xl[0][n >> 3][c][n & 7] = bf16_hi(vals[i] - bf16_f(h));
    }
  }
  // per-lane drive prefetch for step 1 (element (r,nt): chain q*4+r, col n0+nt*16+c16)
  float vnext[8];
  if (MODE != 0) {
#pragma unroll
    for (int r = 0; r < 4; r++)
#pragma unroll
      for (int nt = 0; nt < 2; nt++) {
        int cg = blk * 16 + q * 4 + r;
        int drow = (MODE == 1) ? 1 : 0;
        vnext[r * 2 + nt] = V[((size_t)cg * 32 + drow) * 256 + n0 + nt * 16 + c16];
      }
  }
  __syncthreads();
  for (int s = 1; s <= STEPS; s++) {
    int cur = (s - 1) & 1, nxt = s & 1;
    // MODE 2: flush rows s-4..s-1 (slots row%5) — reads race-free vs writes (mod-5 disjoint)
    if (MODE == 2 && s >= 5 && ((s - 1) & 3) == 0) {
      int rbase = s - 4;
      for (int e = t; e < 4096; e += 512) {
        int slot = e >> 10;
        int rem = e & 1023;
        int c = rem >> 6, qq = (rem & 63) * 4;
        int row = rbase + slot;
        int cg = blk * 16 + c;
        *(float4*)(Out + ((size_t)cg * 32 + row) * 256 + qq) = *(const float4*)&hist[row % 5][c][qq];
      }
    }
    // drive: consume prefetched, issue next step's loads (hidden under MFMAs)
    float vc[8];
    if (MODE != 0) {
#pragma unroll
      for (int i2 = 0; i2 < 8; i2++) vc[i2] = vnext[i2];
      if (s < STEPS) {
        int drow = (MODE == 1) ? (s + 1) : s;
#pragma unroll
        for (int r = 0; r < 4; r++)
#pragma unroll
          for (int nt = 0; nt < 2; nt++)
            vnext[r * 2 + nt] =
                V[((size_t)(blk * 16 + q * 4 + r) * 32 + drow) * 256 + n0 + nt * 16 + c16];
      }
    }
    // pin frags: rw asm operand => value must live in VGPRs, reload illegal
#pragma unroll
    for (int nt = 0; nt < 2; nt++)
#pragma unroll
      for (int kt = 0; kt < 8; kt++) {
        asm volatile("" : "+v"(bh[nt][kt]));
        asm volatile("" : "+v"(bl[nt][kt]));
      }
    float4v a0h = {0.f, 0.f, 0.f, 0.f}, a1h = {0.f, 0.f, 0.f, 0.f};
    float4v a0l = {0.f, 0.f, 0.f, 0.f}, a1l = {0.f, 0.f, 0.f, 0.f};
    float4v a0c = {0.f, 0.f, 0.f, 0.f}, a1c = {0.f, 0.f, 0.f, 0.f};
#pragma unroll
    for (int kt = 0; kt < 8; kt++) {
      short8 ah = *(const short8*)&xh[cur][kt * 4 + q][c16][0];
      short8 al = *(const short8*)&xl[cur][kt * 4 + q][c16][0];
      a0h = __builtin_amdgcn_mfma_f32_16x16x32_bf16(ah, bh[0][kt], a0h, 0, 0, 0);
      a1h = __builtin_amdgcn_mfma_f32_16x16x32_bf16(ah, bh[1][kt], a1h, 0, 0, 0);
      a0l = __builtin_amdgcn_mfma_f32_16x16x32_bf16(al, bh[0][kt], a0l, 0, 0, 0);
      a1l = __builtin_amdgcn_mfma_f32_16x16x32_bf16(al, bh[1][kt], a1l, 0, 0, 0);
      a0c = __builtin_amdgcn_mfma_f32_16x16x32_bf16(ah, bl[0][kt], a0c, 0, 0, 0);
      a1c = __builtin_amdgcn_mfma_f32_16x16x32_bf16(ah, bl[1][kt], a1c, 0, 0, 0);
    }
    // epilogue: C/D layout chain=(q*4+r), col=c16 (m89-verified)
#pragma unroll
    for (int nt = 0; nt < 2; nt++) {
#pragma unroll
      for (int r = 0; r < 4; r++) {
        int c = q * 4 + r;
        int n = n0 + nt * 16 + c16;
        float val = (nt == 0) ? (a0h[r] + a0l[r] + a0c[r]) : (a1h[r] + a1l[r] + a1c[r]);
        if (MODE != 0) val += vc[r * 2 + nt];
        int cg = blk * 16 + c;
        if (MODE == 2) hist[s % 5][c][n] = val;
        if (MODE == 1 && s == STEPS) Out[(size_t)cg * 256 + n] = val;
        if (MODE == 0 && s == STEPS) {
          ushort_t h2 = bf16_hi(val);
          Out[(size_t)n * 256 + cg] = val;
          OutH[(size_t)n * 256 + cg] = h2;
          OutL[(size_t)n * 256 + cg] = bf16_hi(val - bf16_f(h2));
        }
        ushort_t h = bf16_hi(val);
        xh[nxt][n >> 3][c][n & 7] = h;
        xl[nxt][n >> 3][c][n & 7] = bf16_hi(val - bf16_f(h));
      }
    }
    __syncthreads();
  }
  if (MODE == 2) {   // final rows 29,30,31
    for (int e = t; e < 3072; e += 512) {
      int slot = e >> 10;
      int rem = e & 1023;
      int c = rem >> 6, qq = (rem & 63) * 4;
      int row = 29 + slot;
      int cg = blk * 16 + c;
      *(float4*)(Out + ((size_t)cg * 32 + row) * 256 + qq) = *(const float4*)&hist[row % 5][c][qq];
    }
  }
}

// ---------------------------------------------------------------------------
// fp32 GEMM for the drive: C[M][256] = A[M][K] @ B[K][256], BM=BN=128, BK=8.
__global__ __launch_bounds__(256) void gemm128(const float* __restrict__ A, const float* __restrict__ B,
                                               float* __restrict__ C, int M, int K) {
  int m0 = blockIdx.x * 128, n0 = blockIdx.y * 128;
  __shared__ float As[8][128];
  __shared__ float Bs[8][128];
  int tid = threadIdx.x;
  int am = tid >> 1, akc = (tid & 1) * 4;
  int bk = tid >> 5, bn = (tid & 31) * 4;
  int ty = tid >> 4, tx = tid & 15;
  float acc[8][8] = {{0.f}};
  for (int kt = 0; kt < K; kt += 8) {
    float4 av = make_float4(0.f, 0.f, 0.f, 0.f);
    if (m0 + am < M) av = *(const float4*)(A + (size_t)(m0 + am) * K + kt + akc);
    float4 bv = *(const float4*)(B + (size_t)(kt + bk) * 256 + n0 + bn);
    __syncthreads();
    As[akc + 0][am] = av.x;
    As[akc + 1][am] = av.y;
    As[akc + 2][am] = av.z;
    As[akc + 3][am] = av.w;
    *(float4*)&Bs[bk][bn] = bv;
    __syncthreads();
#pragma unroll
    for (int kk = 0; kk < 8; kk++) {
      float4 a0 = *(const float4*)&As[kk][ty * 8];
      float4 a1 = *(const float4*)&As[kk][ty * 8 + 4];
      float4 b0 = *(const float4*)&Bs[kk][tx * 8];
      float4 b1 = *(const float4*)&Bs[kk][tx * 8 + 4];
      float ar[8] = {a0.x, a0.y, a0.z, a0.w, a1.x, a1.y, a1.z, a1.w};
      float br[8] = {b0.x, b0.y, b0.z, b0.w, b1.x, b1.y, b1.z, b1.w};
#pragma unroll
      for (int i = 0; i < 8; i++)
#pragma unroll
        for (int j = 0; j < 8; j++) acc[i][j] += ar[i] * br[j];
    }
  }
#pragma unroll
  for (int i = 0; i < 8; i++) {
    int row = m0 + ty * 8 + i;
    if (row < M) {
      *(float4*)&C[(size_t)row * 256 + n0 + tx * 8] = make_float4(acc[i][0], acc[i][1], acc[i][2], acc[i][3]);
      *(float4*)&C[(size_t)row * 256 + n0 + tx * 8 + 4] = make_float4(acc[i][4], acc[i][5], acc[i][6], acc[i][7]);
    }
  }
}

// AT = A^T (256x256)
__global__ __launch_bounds__(256) void transpose_at(const float* __restrict__ A, float* __restrict__ AT) {
  __shared__ float tile[64][65];
  int bx = blockIdx.x & 3, by = blockIdx.x >> 2;
  int r0 = by * 64, c0 = bx * 64;
  int t = threadIdx.x;
  int lr = t >> 4, lc = (t & 15) * 4;
  for (int rr = lr; rr < 64; rr += 16) {
    float4 v = *(const float4*)(A + (size_t)(r0 + rr) * 256 + c0 + lc);
    tile[rr][lc + 0] = v.x; tile[rr][lc + 1] = v.y; tile[rr][lc + 2] = v.z; tile[rr][lc + 3] = v.w;
  }
  __syncthreads();
  for (int rr = lr; rr < 64; rr += 16) {
    float4 v = make_float4(tile[lc + 0][rr], tile[lc + 1][rr], tile[lc + 2][rr], tile[lc + 3][rr]);
    *(float4*)(AT + (size_t)(c0 + rr) * 256 + r0 + lc) = v;
  }
}

// Unit responses through one Dopri5 step: cols 0..255 -> R fp32 + bf16 hi/lo
// split; cols 256..383 -> Hermite-folded tap matrices transposed into FcatT.
__global__ __launch_bounds__(256) void unit_resp(const float* __restrict__ AT,
                                                 const float* __restrict__ Bm,
                                                 float* __restrict__ Rout,
                                                 ushort_t* __restrict__ Rh,
                                                 ushort_t* __restrict__ Rl,
                                                 float* __restrict__ FcatT) {
  int w = blockIdx.x;
  int i = threadIdx.x;
  __shared__ float xs4[256][4];

  const float AA[6][5] = {
      {0.f, 0.f, 0.f, 0.f, 0.f},
      {0.2f, 0.f, 0.f, 0.f, 0.f},
      {3.f / 40.f, 9.f / 40.f, 0.f, 0.f, 0.f},
      {44.f / 45.f, -56.f / 15.f, 32.f / 9.f, 0.f, 0.f},
      {19372.f / 6561.f, -25360.f / 2187.f, 64448.f / 6561.f, -212.f / 729.f, 0.f},
      {9017.f / 3168.f, -355.f / 33.f, 46732.f / 5247.f, 49.f / 176.f, -5103.f / 18656.f}};
  const float BB[6] = {35.f / 384.f, 0.f, 500.f / 1113.f, 125.f / 192.f, -2187.f / 6784.f, 11.f / 84.f};
  const float sv[6] = {0.f, 0.2f, 0.3f, 0.8f, 8.f / 9.f, 1.f};
  float Hm[6][4];
#pragma unroll
  for (int s = 0; s < 6; s++) {
    float ss = sv[s], s2 = ss * ss, s3 = s2 * ss;
    Hm[s][0] = 2.f * s3 - 3.f * s2 + 1.f;
    Hm[s][1] = s3 - 2.f * s2 + ss;
    Hm[s][2] = -2.f * s3 + 3.f * s2;
    Hm[s][3] = s3 - s2;
  }

  float xc[4];
  float kreg[6][4];
#pragma unroll
  for (int s = 0; s < 6; s++)
#pragma unroll
    for (int cc = 0; cc < 4; cc++) kreg[s][cc] = 0.f;

  int col[4], isF[4], tt[4];
  float brow[4];
#pragma unroll
  for (int cc = 0; cc < 4; cc++) {
    col[cc] = w * 4 + cc;
    if (col[cc] < 256) {
      isF[cc] = 0; tt[cc] = 0; brow[cc] = 0.f;
      xc[cc] = (i == col[cc]) ? 1.f : 0.f;
    } else {
      isF[cc] = 1; xc[cc] = 0.f;
      int f = col[cc] - 256;
      tt[cc] = f >> 5;
      brow[cc] = Bm[i * 32 + (f & 31)];
    }
  }
  float bh[6][4];
#pragma unroll
  for (int s = 0; s < 6; s++)
#pragma unroll
    for (int cc = 0; cc < 4; cc++) {
      float hv = (tt[cc] == 0) ? Hm[s][0] : ((tt[cc] == 1) ? Hm[s][1] : ((tt[cc] == 2) ? Hm[s][2] : Hm[s][3]));
      bh[s][cc] = isF[cc] ? hv * brow[cc] : 0.f;
    }

#pragma unroll
  for (int s = 0; s < 6; s++) {
#pragma unroll
    for (int cc = 0; cc < 4; cc++) {
      float v = xc[cc];
#pragma unroll
      for (int j = 0; j < 5; j++)
        if (j < s) v += AA[s][j] * kreg[j][cc];
      xs4[i][cc] = v;
    }
    __syncthreads();
    float ac[4] = {0.f, 0.f, 0.f, 0.f};
#pragma unroll 4
    for (int j = 0; j < 256; j++) {
      float a = AT[(size_t)j * 256 + i];
      float4 xv = *(const float4*)xs4[j];
      ac[0] += a * xv.x;
      ac[1] += a * xv.y;
      ac[2] += a * xv.z;
      ac[3] += a * xv.w;
    }
#pragma unroll
    for (int cc = 0; cc < 4; cc++) kreg[s][cc] = ac[cc] + bh[s][cc];
    __syncthreads();
  }
#pragma unroll
  for (int cc = 0; cc < 4; cc++) {
    float o = xc[cc];
#pragma unroll
    for (int s = 0; s < 6; s++) o += BB[s] * kreg[s][cc];
    if (!isF[cc]) {
      Rout[(size_t)i * 256 + col[cc]] = o;
      ushort_t h = bf16_hi(o);
      Rh[(size_t)i * 256 + col[cc]] = h;
      Rl[(size_t)i * 256 + col[cc]] = bf16_hi(o - bf16_f(h));
    } else {
      FcatT[(size_t)(col[cc] - 256) * 256 + i] = o;
    }
  }
}

// Wtap[n][tap] = {u_n, m_n, u_{n+1}, m_{n+1}} taps; row 32767 = 0 (pad).
__global__ __launch_bounds__(128) void build_wtap(const float* __restrict__ u, float* __restrict__ Wtap) {
  int n = blockIdx.x;
  int tid = threadIdx.x;
  int t = tid >> 5, c = tid & 31;
  float val = 0.f;
  if (n < TPTS - 1) {
    if (t == 0) val = u[(size_t)n * 32 + c];
    else if (t == 2) val = u[(size_t)(n + 1) * 32 + c];
    else {
      int k = (t == 1) ? n : n + 1;
      if (k == 0) val = u[32 + c] - u[c];
      else if (k == TPTS - 1) val = u[(size_t)(TPTS - 1) * 32 + c] - u[(size_t)(TPTS - 2) * 32 + c];
      else val = 0.5f * (u[(size_t)(k + 1) * 32 + c] - u[(size_t)(k - 1) * 32 + c]);
    }
  }
  Wtap[(size_t)n * 128 + tid] = val;
}

// Top-level (stride-1024) starts; ||R^1024|| ~ 6e-5 so 2-term series suffices.
__global__ __launch_bounds__(256) void top_scan(const float* __restrict__ V2, const float* __restrict__ x0,
                                                const float* __restrict__ R1024, float* __restrict__ X2) {
  int k = blockIdx.x, i = threadIdx.x;
  if (k == 0) { X2[i] = x0[i]; return; }
  __shared__ float prev[256];
  const float* pv = (k == 1) ? x0 : (V2 + (size_t)(k - 2) * 256);
  prev[i] = pv[i];
  __syncthreads();
  float acc = V2[(size_t)(k - 1) * 256 + i];
  const float* rr = R1024 + (size_t)i * 256;
  for (int j = 0; j < 256; j += 4) {
    float4 rv = *(const float4*)(rr + j);
    acc += rv.x * prev[j] + rv.y * prev[j + 1] + rv.z * prev[j + 2] + rv.w * prev[j + 3];
  }
  X2[(size_t)k * 256 + i] = acc;
}

// y = x @ C^T + u @ D^T
__global__ __launch_bounds__(256) void y_kernel(const float* __restrict__ x, const float* __restrict__ u,
                                                const float* __restrict__ Cm, const float* __restrict__ Dm,
                                                float* __restrict__ y) {
  __shared__ float Cs[32][260];
  __shared__ float Ds[32][32];
  __shared__ float xs[8][256];
  __shared__ float us[8][32];
  int tid = threadIdx.x;
  for (int k = tid; k < 8192; k += 256) Cs[k >> 8][k & 255] = Cm[k];
  for (int k = tid; k < 1024; k += 256) Ds[k >> 5][k & 31] = Dm[k];
  int o = tid & 31, rr = tid >> 5;
  int n0 = blockIdx.x * 64;
  for (int g = 0; g < 8; g++) {
    int nb = n0 + g * 8;
    __syncthreads();
    for (int k = tid; k < 2048; k += 256)
      xs[k >> 8][k & 255] = x[(size_t)(nb + (k >> 8)) * 256 + (k & 255)];
    for (int k = tid; k < 256; k += 256)
      us[k >> 5][k & 31] = u[(size_t)(nb + (k >> 5)) * 32 + (k & 31)];
    __syncthreads();
    float acc = 0.f;
    for (int i = 0; i < 256; i += 4) {
      float4 cv = *(const float4*)&Cs[o][i];
      float4 xv = *(const float4*)&xs[rr][i];
      acc += cv.x * xv.x + cv.y * xv.y + cv.z * xv.z + cv.w * xv.w;
    }
#pragma unroll
    for (int c = 0; c < 32; c += 4) {
      float4 dv = *(const float4*)&Ds[o][c];
      float4 uv = *(const float4*)&us[rr][c];
      acc += dv.x * uv.x + dv.y * uv.y + dv.z * uv.z + dv.w * uv.w;
    }
    y[(size_t)(nb + rr) * 32 + o] = acc;
  }
}

extern "C" void kernel_launch(void* const* d_in, const int* in_sizes, int n_in,
                              void* d_out, int out_size, void* d_ws, size_t ws_size,
                              hipStream_t stream) {
  const float* u  = (const float*)d_in[1];
  const float* x0 = (const float*)d_in[2];
  const float* A  = (const float*)d_in[3];
  const float* Bm = (const float*)d_in[4];
  const float* Cm = (const float*)d_in[5];
  const float* Dm = (const float*)d_in[6];
  float* xout = (float*)d_out;                       // [32768][256]
  float* yout = xout + (size_t)TPTS * 256;           // [32768][32]

  char* wsb = (char*)d_ws;
  size_t off = 0;
  auto alloc = [&](size_t bytes) -> void* {
    void* p = (void*)(wsb + off);
    off = (off + bytes + 255) & ~(size_t)255;
    return p;
  };
  float*    Rfp    = (float*)alloc(65536 * 4);
  ushort_t* Rh     = (ushort_t*)alloc(65536 * 2);
  ushort_t* Rl     = (ushort_t*)alloc(65536 * 2);
  float*    R32fp  = (float*)alloc(65536 * 4);
  ushort_t* R32h   = (ushort_t*)alloc(65536 * 2);
  ushort_t* R32l   = (ushort_t*)alloc(65536 * 2);
  float*    RKfp   = (float*)alloc(65536 * 4);       // R^1024
  ushort_t* RKh    = (ushort_t*)alloc(65536 * 2);
  ushort_t* RKl    = (ushort_t*)alloc(65536 * 2);
  float*    ATm    = (float*)alloc(65536 * 4);
  float*    FcatT  = (float*)alloc(128 * 256 * 4);
  float*    Wtap   = (float*)alloc((size_t)TPTS * 128 * 4);
  float*    V0     = (float*)alloc((size_t)TPTS * 256 * 4);
  float*    V1     = (float*)alloc(1024 * 256 * 4);
  float*    V2     = (float*)alloc(32 * 256 * 4);
  float*    X2     = (float*)alloc(32 * 256 * 4);
  float*    X1     = (float*)alloc(1024 * 256 * 4);
  (void)ws_size; (void)in_sizes; (void)n_in; (void)out_size;

  // 1. A^T, unit responses -> R (fp32 + hi/lo split) and FcatT
  transpose_at<<<dim3(16), dim3(256), 0, stream>>>(A, ATm);
  unit_resp<<<dim3(96), dim3(256), 0, stream>>>(ATm, Bm, Rfp, Rh, Rl, FcatT);

  // 2. R^32 = 32 chained applications of R on unit columns; R^1024 likewise on R^32
  chain_mfma<0><<<dim3(16), dim3(512), 0, stream>>>(Rh, Rl, nullptr, nullptr, R32fp, R32h, R32l);
  chain_mfma<0><<<dim3(16), dim3(512), 0, stream>>>(R32h, R32l, nullptr, nullptr, RKfp, RKh, RKl);

  // 3. Hermite taps and per-step drive v_n (fp32 GEMM, K=128)
  build_wtap<<<dim3(TPTS), dim3(128), 0, stream>>>(u, Wtap);
  gemm128<<<dim3(256, 2), dim3(256), 0, stream>>>(Wtap, FcatT, V0, TPTS, 128);

  // 4. reduces: V1[j] = sum_i R^(31-i) v_{32j+i};  V2[k] = sum_j R32^(31-j) V1[32k+j]
  chain_mfma<1><<<dim3(64), dim3(512), 0, stream>>>(Rh, Rl, nullptr, V0, V1, nullptr, nullptr);
  chain_mfma<1><<<dim3(2), dim3(512), 0, stream>>>(R32h, R32l, nullptr, V1, V2, nullptr, nullptr);

  // 5. top starts, then expand down two levels
  top_scan<<<dim3(32), dim3(256), 0, stream>>>(V2, x0, RKfp, X2);
  chain_mfma<2><<<dim3(2), dim3(512), 0, stream>>>(R32h, R32l, X2, V1, X1, nullptr, nullptr);
  chain_mfma<2><<<dim3(64), dim3(512), 0, stream>>>(Rh, Rl, X1, V0, xout, nullptr, nullptr);

  // 6. outputs y
  y_kernel<<<dim3(512), dim3(256), 0, stream>>>(xout, u, Cm, Dm, yout);
}